// Round 1
// baseline (1117.113 us; speedup 1.0000x reference)
//
#include <hip/hip_runtime.h>
#include <stdint.h>

#define DD 128
#define HN 8
#define HDIM 1024
#define NITEMS 81920
#define EINT 163840
#define NT 4096
#define NV 40000
#define NVPAD 40064
#define EAGG 81920
#define NEG_SLOPE 0.2f
#define SCALE 12.0f

typedef unsigned short u16;
typedef __attribute__((ext_vector_type(8))) short bf16x8;
typedef __attribute__((ext_vector_type(4))) float f32x4;

__device__ __forceinline__ float bf2f(unsigned short u){ return __uint_as_float(((unsigned)u)<<16); }
__device__ __forceinline__ unsigned short f2bf(float f){
  unsigned u = __float_as_uint(f);
  u += 0x7fffu + ((u>>16)&1u);
  return (unsigned short)(u>>16);
}

__global__ __launch_bounds__(256) void k_cast(const float* __restrict__ s, u16* __restrict__ d, int n){
  int i = blockIdx.x*256 + threadIdx.x;
  if (i < n) d[i] = f2bf(s[i]);
}

// hv = normalize(emb[iid]) -> f32 + bf16
__global__ __launch_bounds__(256) void k_hv(const float* __restrict__ emb, const int* __restrict__ iid,
                                            float* __restrict__ hv, u16* __restrict__ hvb, int n){
  int w = (blockIdx.x*256 + threadIdx.x) >> 6;
  int lane = threadIdx.x & 63;
  if (w >= n) return;
  const float* src = emb + (size_t)iid[w]*DD;
  float2 v = *(const float2*)(src + lane*2);
  float ss = v.x*v.x + v.y*v.y;
  #pragma unroll
  for (int m=1;m<64;m<<=1) ss += __shfl_xor(ss, m);
  float inv = 1.f / fmaxf(sqrtf(ss), 1e-12f);
  float a = v.x*inv, b = v.y*inv;
  float2 o; o.x=a; o.y=b;
  *(float2*)(hv + (size_t)w*DD + lane*2) = o;
  hvb[(size_t)w*DD + lane*2]     = f2bf(a);
  hvb[(size_t)w*DD + lane*2 + 1] = f2bf(b);
}

// normalized emb (all 40000 rows) as bf16, padded to 40064 rows (pad = 0)
__global__ __launch_bounds__(256) void k_nemb(const float* __restrict__ emb, u16* __restrict__ nb){
  int w = (blockIdx.x*256 + threadIdx.x) >> 6;
  int lane = threadIdx.x & 63;
  if (w >= NVPAD) return;
  if (w >= NV){ nb[(size_t)w*DD+lane*2]=0; nb[(size_t)w*DD+lane*2+1]=0; return; }
  const float* src = emb + (size_t)w*DD;
  float2 v = *(const float2*)(src + lane*2);
  float ss = v.x*v.x + v.y*v.y;
  #pragma unroll
  for (int m=1;m<64;m<<=1) ss += __shfl_xor(ss, m);
  float inv = 1.f / fmaxf(sqrtf(ss), 1e-12f);
  nb[(size_t)w*DD+lane*2]   = f2bf(v.x*inv);
  nb[(size_t)w*DD+lane*2+1] = f2bf(v.y*inv);
}

// C[m,n] = alpha * sum_k A[m,k]*B[n,k]   (A:[M,K] bf16, B:[N,K] bf16, NT layout)
// 128x128 tile, 4 waves (2x2), mfma_f32_16x16x32_bf16, K multiple of 32, M,N(padded) multiples of 128.
template<int OUT_BF16>
__global__ __launch_bounds__(256) void gemm_nt(const u16* __restrict__ A, const u16* __restrict__ B,
                                               void* __restrict__ C, int M, int N, int K,
                                               float alpha, int ldc, int nvalid){
  __shared__ u16 As[128*32];
  __shared__ u16 Bs[128*32];
  int m0 = blockIdx.x*128, n0 = blockIdx.y*128;
  int t = threadIdx.x, lane = t&63, wid = t>>6;
  int wm = wid>>1, wn = wid&1;
  f32x4 zero = {0.f,0.f,0.f,0.f};
  f32x4 acc[4][4];
  #pragma unroll
  for (int i=0;i<4;i++)
    #pragma unroll
    for (int j=0;j<4;j++) acc[i][j] = zero;
  int lr = lane & 15, lk = (lane>>4)*8;
  for (int k0=0; k0<K; k0+=32){
    #pragma unroll
    for (int cc=0; cc<2; ++cc){
      int c = t + cc*256;          // chunk 0..511; 16B each
      int row = c>>2, col = (c&3)*8;
      *(bf16x8*)(void*)&As[c*8] = *(const bf16x8*)(const void*)&A[(size_t)(m0+row)*K + k0 + col];
      *(bf16x8*)(void*)&Bs[c*8] = *(const bf16x8*)(const void*)&B[(size_t)(n0+row)*K + k0 + col];
    }
    __syncthreads();
    bf16x8 af[4], bfr[4];
    #pragma unroll
    for (int m=0;m<4;m++) af[m]  = *(const bf16x8*)(const void*)&As[(wm*64+m*16+lr)*32 + lk];
    #pragma unroll
    for (int n=0;n<4;n++) bfr[n] = *(const bf16x8*)(const void*)&Bs[(wn*64+n*16+lr)*32 + lk];
    #pragma unroll
    for (int m=0;m<4;m++)
      #pragma unroll
      for (int n=0;n<4;n++)
        acc[m][n] = __builtin_amdgcn_mfma_f32_16x16x32_bf16(af[m], bfr[n], acc[m][n], 0,0,0);
    __syncthreads();
  }
  #pragma unroll
  for (int m=0;m<4;m++)
    #pragma unroll
    for (int n=0;n<4;n++)
      #pragma unroll
      for (int r=0;r<4;r++){
        int row = m0 + wm*64 + m*16 + (lane>>4)*4 + r;
        int col = n0 + wn*64 + n*16 + (lane&15);
        if (col < nvalid){
          float v = acc[m][n][r]*alpha;
          if (OUT_BF16) ((u16*)C)[(size_t)row*ldc + col] = f2bf(v);
          else          ((float*)C)[(size_t)row*ldc + col] = v;
        }
      }
}

// el[n,h] = sum_d fs[n,h,d]*al[h,d];  er likewise. One wave per node; lane covers 16 contiguous elems.
__global__ __launch_bounds__(256) void k_elr(const u16* __restrict__ fs, const float* __restrict__ al,
                                             const float* __restrict__ ar, float* __restrict__ el,
                                             float* __restrict__ er, int n){
  int w = (blockIdx.x*256 + threadIdx.x) >> 6;
  int lane = threadIdx.x & 63;
  if (w >= n) return;
  const bf16x8* fr = (const bf16x8*)(const void*)(fs + (size_t)w*HDIM + lane*16);
  bf16x8 v0 = fr[0], v1 = fr[1];
  int h = lane >> 3;
  int base = (lane & 7)*16;
  float sl = 0.f, sr = 0.f;
  #pragma unroll
  for (int j=0;j<8;j++){
    float f0 = bf2f((unsigned short)v0[j]);
    float f1 = bf2f((unsigned short)v1[j]);
    sl += f0 * al[h*DD + base + j]     + f1 * al[h*DD + base + 8 + j];
    sr += f0 * ar[h*DD + base + j]     + f1 * ar[h*DD + base + 8 + j];
  }
  #pragma unroll
  for (int m=1;m<8;m<<=1){ sl += __shfl_xor(sl,m); sr += __shfl_xor(sr,m); }
  if ((lane&7)==0){ el[(size_t)w*HN + h] = sl; er[(size_t)w*HN + h] = sr; }
}

__global__ __launch_bounds__(256) void k_deg(const int* __restrict__ d, int* __restrict__ cnt, int E){
  int i = blockIdx.x*256+threadIdx.x;
  if (i<E) atomicAdd(&cnt[d[i]], 1);
}

__global__ __launch_bounds__(1024) void k_scan(const int* __restrict__ deg, int* __restrict__ off, int n){
  __shared__ int buf[1024];
  __shared__ int carry;
  int tid = threadIdx.x;
  if (tid==0) carry = 0;
  __syncthreads();
  for (int base=0; base<n; base+=1024){
    int v = (base+tid<n) ? deg[base+tid] : 0;
    buf[tid]=v; __syncthreads();
    for (int ofs=1; ofs<1024; ofs<<=1){
      int x = (tid>=ofs)? buf[tid-ofs] : 0;
      __syncthreads();
      buf[tid] += x;
      __syncthreads();
    }
    int incl = buf[tid];
    if (base+tid < n) off[base+tid] = carry + incl - v;
    __syncthreads();
    if (tid==1023) carry += incl;
    __syncthreads();
  }
  if (tid==0) off[n] = carry;
}

__global__ __launch_bounds__(256) void k_scatter(const int* __restrict__ d, const int* __restrict__ off,
                                                 int* __restrict__ cnt, int* __restrict__ eid, int E){
  int i = blockIdx.x*256+threadIdx.x;
  if (i<E){ int dd = d[i]; int p = off[dd] + atomicAdd(&cnt[dd],1); eid[p]=i; }
}

// One wave per destination node: edge softmax (2 passes) + weighted aggregation + residual + bias + head-max.
__global__ __launch_bounds__(256) void k_gat_agg(const int* __restrict__ off, const int* __restrict__ eid,
    const int* __restrict__ srcArr, const float* __restrict__ el, const float* __restrict__ er,
    const u16* __restrict__ fs, const float* __restrict__ hv, const float* __restrict__ bias,
    float* __restrict__ hout, int addFlag, int n){
  int w = (blockIdx.x*256 + threadIdx.x) >> 6;
  int lane = threadIdx.x & 63;
  if (w >= n) return;
  int h = lane >> 3;                  // lane covers elements [16*lane, 16*lane+16) of the 1024-vec
  float ern = er[(size_t)w*HN + h];
  int lo = off[w], hi = off[w+1];
  float mh = -1e30f;
  for (int idx=lo; idx<hi; ++idx){
    int s = srcArr[eid[idx]];
    float lv = el[(size_t)s*HN + h] + ern;
    lv = (lv >= 0.f) ? lv : NEG_SLOPE*lv;
    mh = fmaxf(mh, lv);
  }
  float denom = 0.f;
  float acc[16];
  #pragma unroll
  for (int j=0;j<16;j++) acc[j]=0.f;
  for (int idx=lo; idx<hi; ++idx){
    int s = srcArr[eid[idx]];
    float lv = el[(size_t)s*HN + h] + ern;
    lv = (lv >= 0.f) ? lv : NEG_SLOPE*lv;
    float wt = expf(lv - mh);
    denom += wt;
    const bf16x8* fr = (const bf16x8*)(const void*)(fs + (size_t)s*HDIM + lane*16);
    bf16x8 v0 = fr[0], v1 = fr[1];
    #pragma unroll
    for (int j=0;j<8;j++){
      acc[j]   += wt * bf2f((unsigned short)v0[j]);
      acc[8+j] += wt * bf2f((unsigned short)v1[j]);
    }
  }
  float inv = (denom > 0.f) ? 1.f/denom : 0.f;
  int dbase = (lane & 7) * 16;
  #pragma unroll
  for (int j=0;j<16;j++)
    acc[j] = acc[j]*inv + hv[(size_t)w*DD + dbase + j] + bias[lane*16 + j];
  // max over heads: lanes differing in bits 3..5 share (d), vary h
  #pragma unroll
  for (int m=8; m<64; m<<=1){
    #pragma unroll
    for (int j=0;j<16;j++){
      float o = __shfl_xor(acc[j], m);
      acc[j] = fmaxf(acc[j], o);
    }
  }
  if (lane < 8){
    if (addFlag){
      #pragma unroll
      for (int j=0;j<16;j++) hout[(size_t)w*DD + lane*16 + j] += acc[j];
    } else {
      #pragma unroll
      for (int j=0;j<16;j++) hout[(size_t)w*DD + lane*16 + j] = acc[j];
    }
  }
}

// hout = normalize(hin) rowwise
__global__ __launch_bounds__(256) void k_h(const float* __restrict__ hin, float* __restrict__ hout, int n){
  int w = (blockIdx.x*256 + threadIdx.x) >> 6;
  int lane = threadIdx.x & 63;
  if (w>=n) return;
  float2 v = *(const float2*)(hin + (size_t)w*DD + lane*2);
  float ss = v.x*v.x + v.y*v.y;
  #pragma unroll
  for (int m=1;m<64;m<<=1) ss += __shfl_xor(ss,m);
  float inv = 1.f/fmaxf(sqrtf(ss),1e-12f);
  float2 o; o.x=v.x*inv; o.y=v.y*inv;
  *(float2*)(hout + (size_t)w*DD + lane*2) = o;
}

// cat[i] = [ h[agg_src[i]] | pos_emb[pid[i]] ]  (bf16, [EAGG,256])
__global__ __launch_bounds__(256) void k_cat(const float* __restrict__ h, const float* __restrict__ pemb,
    const int* __restrict__ pid, const int* __restrict__ asrc, u16* __restrict__ cat){
  int idx = blockIdx.x*256 + threadIdx.x;
  if (idx >= EAGG*DD) return;
  int i = idx / DD, d = idx % DD;
  int s = asrc[i], p = pid[i];
  cat[(size_t)i*256 + d]      = f2bf(h[(size_t)s*DD + d]);
  cat[(size_t)i*256 + DD + d] = f2bf(pemb[(size_t)p*DD + d]);
}

// w[i] = sum_j tanh(ep[i,j]) * target_emb[tid[agg_dst[i]], j]
__global__ __launch_bounds__(256) void k_w(const float* __restrict__ ep, const int* __restrict__ adst,
    const int* __restrict__ tid_, const float* __restrict__ temb, float* __restrict__ w){
  int i = (blockIdx.x*256 + threadIdx.x) >> 6;
  int lane = threadIdx.x & 63;
  if (i >= EAGG) return;
  int t = adst[i];
  int tt = tid_[t];
  float e0 = tanhf(ep[(size_t)i*DD + lane*2]);
  float e1 = tanhf(ep[(size_t)i*DD + lane*2 + 1]);
  float2 te = *(const float2*)(temb + (size_t)tt*DD + lane*2);
  float s = e0*te.x + e1*te.y;
  #pragma unroll
  for (int m=1;m<64;m<<=1) s += __shfl_xor(s,m);
  if (lane==0) w[i] = s;
}

__device__ __forceinline__ int lbound(const int* a, int n, int key){
  int lo=0, hi=n;
  while (lo<hi){ int mid=(lo+hi)>>1; if (a[mid]<key) lo=mid+1; else hi=mid; }
  return lo;
}

// per-target: sr_g (segment sum over sorted agg_dst), concat with h[last], matmul fc_sr, normalize -> nsr bf16
__global__ __launch_bounds__(256) void k_sr(const float* __restrict__ h, const float* __restrict__ w,
    const int* __restrict__ asrc, const int* __restrict__ adst, const int* __restrict__ lastn,
    const float* __restrict__ fcsr, u16* __restrict__ nsr){
  __shared__ float cat[256];
  __shared__ float red[128];
  __shared__ int lohi[2];
  int t = blockIdx.x, tid = threadIdx.x;
  if (tid == 0){ lohi[0] = lbound(adst, EAGG, t); lohi[1] = lbound(adst, EAGG, t+1); }
  __syncthreads();
  int lo = lohi[0], hi = lohi[1];
  if (tid < DD){
    float a = 0.f;
    for (int i=lo;i<hi;++i) a += h[(size_t)asrc[i]*DD + tid] * w[i];
    cat[tid] = a;
  } else {
    int d = tid - DD;
    cat[DD + d] = h[(size_t)lastn[t]*DD + d];
  }
  __syncthreads();
  float s = 0.f;
  if (tid < DD){
    const float* row = fcsr + (size_t)tid*256;
    #pragma unroll 8
    for (int k=0;k<256;++k) s += cat[k]*row[k];
    red[tid] = s*s;
  }
  __syncthreads();
  for (int st=64; st>0; st>>=1){
    if (tid < st) red[tid] += red[tid+st];
    __syncthreads();
  }
  if (tid < DD){
    float inv = 1.f/fmaxf(sqrtf(red[0]),1e-12f);
    nsr[(size_t)t*DD + tid] = f2bf(s*inv);
  }
}

extern "C" void kernel_launch(void* const* d_in, const int* in_sizes, int n_in,
                              void* d_out, int out_size, void* d_ws, size_t ws_size,
                              hipStream_t stream){
  (void)in_sizes; (void)n_in; (void)out_size; (void)ws_size;
  const int*   iid   = (const int*)d_in[0];
  const int*   tid_  = (const int*)d_in[1];
  const int*   pid   = (const int*)d_in[2];
  const int*   src_i = (const int*)d_in[3];
  const int*   dst_i = (const int*)d_in[4];
  const int*   asrc  = (const int*)d_in[5];
  const int*   adst  = (const int*)d_in[6];
  const int*   lastn = (const int*)d_in[7];
  const float* emb   = (const float*)d_in[8];
  const float* pemb  = (const float*)d_in[9];
  const float* temb  = (const float*)d_in[10];
  const float* fc1   = (const float*)d_in[11];
  const float* al1   = (const float*)d_in[12];
  const float* ar1   = (const float*)d_in[13];
  const float* b1    = (const float*)d_in[14];
  const float* fc2   = (const float*)d_in[15];
  const float* al2   = (const float*)d_in[16];
  const float* ar2   = (const float*)d_in[17];
  const float* b2    = (const float*)d_in[18];
  const float* qw    = (const float*)d_in[19];
  const float* fcsr  = (const float*)d_in[20];

  char* ws = (char*)d_ws;
  size_t o = 0;
  auto alc = [&](size_t b)->char*{ char* r = ws + o; o += (b + 511) & ~(size_t)511; return r; };
  float* hv   = (float*)alc((size_t)NITEMS*DD*4);      // 42 MB  (later reused to hold h)
  u16*   hvb  = (u16*)  alc((size_t)NITEMS*DD*2);      // 21 MB
  float* h1   = (float*)alc((size_t)NITEMS*DD*4);      // 42 MB  (h1, then h1+h2)
  float* el   = (float*)alc((size_t)NITEMS*HN*4);
  float* er   = (float*)alc((size_t)NITEMS*HN*4);
  int*   off  = (int*)  alc((size_t)(NITEMS+1)*4);
  int*   cnt  = (int*)  alc((size_t)NITEMS*4);
  int*   eid  = (int*)  alc((size_t)EINT*4);
  u16*   wfc  = (u16*)  alc((size_t)HDIM*DD*2);
  u16*   qwb  = (u16*)  alc((size_t)DD*256*2);
  float* wv   = (float*)alc((size_t)EAGG*4);
  u16*   nsr  = (u16*)  alc((size_t)NT*DD*2);
  u16*   nemb = (u16*)  alc((size_t)NVPAD*DD*2);       // 10 MB
  u16*   fsb  = (u16*)  alc((size_t)NITEMS*HDIM*2);    // 168 MB (fs; later aliased by cat + e_pre)
  u16*   catb = fsb;
  float* ep   = (float*)((char*)fsb + (size_t)EAGG*256*2);

  // common precompute
  k_hv  <<<NITEMS/4, 256, 0, stream>>>(emb, iid, hv, hvb, NITEMS);
  k_nemb<<<NVPAD/4,  256, 0, stream>>>(emb, nemb);

  // ---- GAT1 (graph: src_i -> dst_i) ----
  k_cast<<<(HDIM*DD+255)/256, 256, 0, stream>>>(fc1, wfc, HDIM*DD);
  gemm_nt<1><<<dim3(NITEMS/128, HDIM/128), 256, 0, stream>>>(hvb, wfc, fsb, NITEMS, HDIM, DD, 1.f, HDIM, HDIM);
  k_elr<<<NITEMS/4, 256, 0, stream>>>(fsb, al1, ar1, el, er, NITEMS);
  hipMemsetAsync(cnt, 0, (size_t)NITEMS*4, stream);
  k_deg<<<(EINT+255)/256, 256, 0, stream>>>(dst_i, cnt, EINT);
  k_scan<<<1, 1024, 0, stream>>>(cnt, off, NITEMS);
  hipMemsetAsync(cnt, 0, (size_t)NITEMS*4, stream);
  k_scatter<<<(EINT+255)/256, 256, 0, stream>>>(dst_i, off, cnt, eid, EINT);
  k_gat_agg<<<NITEMS/4, 256, 0, stream>>>(off, eid, src_i, el, er, fsb, hv, b1, h1, 0, NITEMS);

  // ---- GAT2 (reversed graph: dst_i -> src_i), accumulate into h1 ----
  k_cast<<<(HDIM*DD+255)/256, 256, 0, stream>>>(fc2, wfc, HDIM*DD);
  gemm_nt<1><<<dim3(NITEMS/128, HDIM/128), 256, 0, stream>>>(hvb, wfc, fsb, NITEMS, HDIM, DD, 1.f, HDIM, HDIM);
  k_elr<<<NITEMS/4, 256, 0, stream>>>(fsb, al2, ar2, el, er, NITEMS);
  hipMemsetAsync(cnt, 0, (size_t)NITEMS*4, stream);
  k_deg<<<(EINT+255)/256, 256, 0, stream>>>(src_i, cnt, EINT);
  k_scan<<<1, 1024, 0, stream>>>(cnt, off, NITEMS);
  hipMemsetAsync(cnt, 0, (size_t)NITEMS*4, stream);
  k_scatter<<<(EINT+255)/256, 256, 0, stream>>>(src_i, off, cnt, eid, EINT);
  k_gat_agg<<<NITEMS/4, 256, 0, stream>>>(off, eid, dst_i, el, er, fsb, hv, b2, h1, 1, NITEMS);

  // h = normalize(h1+h2)  (stored into hv buffer, fs region now free)
  k_h<<<NITEMS/4, 256, 0, stream>>>(h1, hv, NITEMS);

  // ---- PosAggregator ----
  k_cast<<<(DD*256+255)/256, 256, 0, stream>>>(qw, qwb, DD*256);
  k_cat<<<(EAGG*DD)/256, 256, 0, stream>>>(hv, pemb, pid, asrc, catb);
  gemm_nt<0><<<dim3(EAGG/128, 1), 256, 0, stream>>>(catb, qwb, ep, EAGG, DD, 256, 1.f, DD, DD);
  k_w<<<EAGG/4, 256, 0, stream>>>(ep, adst, tid_, temb, wv);
  k_sr<<<NT, 256, 0, stream>>>(hv, wv, asrc, adst, lastn, fcsr, nsr);

  // ---- scores = SCALE * nsr @ nemb^T ----
  gemm_nt<0><<<dim3(NT/128, NVPAD/128), 256, 0, stream>>>(nsr, nemb, (float*)d_out, NT, NVPAD, DD, SCALE, NV, NV);
}

// Round 2
// 812.953 us; speedup vs baseline: 1.3741x; 1.3741x over previous
//
#include <hip/hip_runtime.h>
#include <stdint.h>

#define DD 128
#define HN 8
#define HDIM 1024
#define NITEMS 81920
#define EINT 163840
#define NT 4096
#define NV 40000
#define NVPAD 40064
#define EAGG 81920
#define NEG_SLOPE 0.2f
#define SCALE 12.0f

typedef unsigned short u16;
typedef __attribute__((ext_vector_type(8))) short bf16x8;
typedef __attribute__((ext_vector_type(4))) float f32x4;
typedef __attribute__((ext_vector_type(4))) unsigned short u16x4;

__device__ __forceinline__ float bf2f(unsigned short u){ return __uint_as_float(((unsigned)u)<<16); }
__device__ __forceinline__ unsigned short f2bf(float f){
  unsigned u = __float_as_uint(f);
  u += 0x7fffu + ((u>>16)&1u);
  return (unsigned short)(u>>16);
}

__global__ __launch_bounds__(256) void k_cast(const float* __restrict__ s, u16* __restrict__ d, int n){
  int i = blockIdx.x*256 + threadIdx.x;
  if (i < n) d[i] = f2bf(s[i]);
}

// U[g*8+h][k], g: 0=l1,1=r1,2=l2,3=r2 ; rows 32..127 pre-zeroed by memset
__global__ __launch_bounds__(128) void k_prep_u(const float* __restrict__ fc1, const float* __restrict__ al1,
    const float* __restrict__ ar1, const float* __restrict__ fc2, const float* __restrict__ al2,
    const float* __restrict__ ar2, u16* __restrict__ U){
  int h = blockIdx.x;     // 0..7
  int k = threadIdx.x;    // 0..127
  float s0=0,s1=0,s2=0,s3=0;
  for (int d=0; d<DD; ++d){
    float w1 = fc1[(size_t)(h*DD+d)*DD + k];
    float w2 = fc2[(size_t)(h*DD+d)*DD + k];
    s0 += w1*al1[h*DD+d];
    s1 += w1*ar1[h*DD+d];
    s2 += w2*al2[h*DD+d];
    s3 += w2*ar2[h*DD+d];
  }
  U[(size_t)(0*8+h)*DD + k] = f2bf(s0);
  U[(size_t)(1*8+h)*DD + k] = f2bf(s1);
  U[(size_t)(2*8+h)*DD + k] = f2bf(s2);
  U[(size_t)(3*8+h)*DD + k] = f2bf(s3);
}

// hv = normalize(emb[iid]) -> f32 + bf16
__global__ __launch_bounds__(256) void k_hv(const float* __restrict__ emb, const int* __restrict__ iid,
                                            float* __restrict__ hv, u16* __restrict__ hvb, int n){
  int w = (blockIdx.x*256 + threadIdx.x) >> 6;
  int lane = threadIdx.x & 63;
  if (w >= n) return;
  const float* src = emb + (size_t)iid[w]*DD;
  float2 v = *(const float2*)(src + lane*2);
  float ss = v.x*v.x + v.y*v.y;
  #pragma unroll
  for (int m=1;m<64;m<<=1) ss += __shfl_xor(ss, m);
  float inv = 1.f / fmaxf(sqrtf(ss), 1e-12f);
  float a = v.x*inv, b = v.y*inv;
  float2 o; o.x=a; o.y=b;
  *(float2*)(hv + (size_t)w*DD + lane*2) = o;
  hvb[(size_t)w*DD + lane*2]     = f2bf(a);
  hvb[(size_t)w*DD + lane*2 + 1] = f2bf(b);
}

// normalized emb (all 40000 rows) as bf16, padded to 40064 rows (pad = 0)
__global__ __launch_bounds__(256) void k_nemb(const float* __restrict__ emb, u16* __restrict__ nb){
  int w = (blockIdx.x*256 + threadIdx.x) >> 6;
  int lane = threadIdx.x & 63;
  if (w >= NVPAD) return;
  if (w >= NV){ nb[(size_t)w*DD+lane*2]=0; nb[(size_t)w*DD+lane*2+1]=0; return; }
  const float* src = emb + (size_t)w*DD;
  float2 v = *(const float2*)(src + lane*2);
  float ss = v.x*v.x + v.y*v.y;
  #pragma unroll
  for (int m=1;m<64;m<<=1) ss += __shfl_xor(ss, m);
  float inv = 1.f / fmaxf(sqrtf(ss), 1e-12f);
  nb[(size_t)w*DD+lane*2]   = f2bf(v.x*inv);
  nb[(size_t)w*DD+lane*2+1] = f2bf(v.y*inv);
}

// C[m,n] = alpha * sum_k A[m,k]*B[n,k]   (A:[M,K] bf16, B:[N,K] bf16, NT layout)
template<int OUT_BF16>
__global__ __launch_bounds__(256) void gemm_nt(const u16* __restrict__ A, const u16* __restrict__ B,
                                               void* __restrict__ C, int M, int N, int K,
                                               float alpha, int ldc, int nvalid){
  __shared__ u16 As[128*32];
  __shared__ u16 Bs[128*32];
  int m0 = blockIdx.x*128, n0 = blockIdx.y*128;
  int t = threadIdx.x, lane = t&63, wid = t>>6;
  int wm = wid>>1, wn = wid&1;
  f32x4 zero = {0.f,0.f,0.f,0.f};
  f32x4 acc[4][4];
  #pragma unroll
  for (int i=0;i<4;i++)
    #pragma unroll
    for (int j=0;j<4;j++) acc[i][j] = zero;
  int lr = lane & 15, lk = (lane>>4)*8;
  for (int k0=0; k0<K; k0+=32){
    #pragma unroll
    for (int cc=0; cc<2; ++cc){
      int c = t + cc*256;          // chunk 0..511; 16B each
      int row = c>>2, col = (c&3)*8;
      *(bf16x8*)(void*)&As[c*8] = *(const bf16x8*)(const void*)&A[(size_t)(m0+row)*K + k0 + col];
      *(bf16x8*)(void*)&Bs[c*8] = *(const bf16x8*)(const void*)&B[(size_t)(n0+row)*K + k0 + col];
    }
    __syncthreads();
    bf16x8 af[4], bfr[4];
    #pragma unroll
    for (int m=0;m<4;m++) af[m]  = *(const bf16x8*)(const void*)&As[(wm*64+m*16+lr)*32 + lk];
    #pragma unroll
    for (int n=0;n<4;n++) bfr[n] = *(const bf16x8*)(const void*)&Bs[(wn*64+n*16+lr)*32 + lk];
    #pragma unroll
    for (int m=0;m<4;m++)
      #pragma unroll
      for (int n=0;n<4;n++)
        acc[m][n] = __builtin_amdgcn_mfma_f32_16x16x32_bf16(af[m], bfr[n], acc[m][n], 0,0,0);
    __syncthreads();
  }
  #pragma unroll
  for (int m=0;m<4;m++)
    #pragma unroll
    for (int n=0;n<4;n++)
      #pragma unroll
      for (int r=0;r<4;r++){
        int row = m0 + wm*64 + m*16 + (lane>>4)*4 + r;
        int col = n0 + wn*64 + n*16 + (lane&15);
        if (col < nvalid){
          float v = acc[m][n][r]*alpha;
          if (OUT_BF16) ((u16*)C)[(size_t)row*ldc + col] = f2bf(v);
          else          ((float*)C)[(size_t)row*ldc + col] = v;
        }
      }
}

__global__ __launch_bounds__(256) void k_deg(const int* __restrict__ d, int* __restrict__ cnt, int E){
  int i = blockIdx.x*256+threadIdx.x;
  if (i<E) atomicAdd(&cnt[d[i]], 1);
}

// hierarchical exclusive scan over n values (n = NITEMS), 3 kernels
__global__ __launch_bounds__(256) void k_scan_a(const int* __restrict__ deg, int* __restrict__ off,
                                                int* __restrict__ bsum, int* __restrict__ cnt, int n){
  __shared__ int buf[256];
  int b = blockIdx.x, t = threadIdx.x, i = b*256+t;
  int v = (i<n)? deg[i] : 0;
  buf[t] = v; __syncthreads();
  #pragma unroll
  for (int ofs=1; ofs<256; ofs<<=1){
    int x = (t>=ofs)? buf[t-ofs] : 0;
    __syncthreads();
    buf[t] += x;
    __syncthreads();
  }
  if (i<n){ off[i] = buf[t]-v; cnt[i] = 0; }
  if (t==255) bsum[b] = buf[255];
}

__global__ __launch_bounds__(512) void k_scan_b(int* __restrict__ bsum, int* __restrict__ off, int nb, int n){
  __shared__ int buf[512];
  int t = threadIdx.x;
  int v = (t<nb)? bsum[t] : 0;
  buf[t]=v; __syncthreads();
  #pragma unroll
  for (int ofs=1; ofs<512; ofs<<=1){
    int x=(t>=ofs)?buf[t-ofs]:0; __syncthreads(); buf[t]+=x; __syncthreads();
  }
  if (t<nb) bsum[t] = buf[t]-v;   // exclusive block prefix
  if (t==511) off[n] = buf[511];  // grand total
}

__global__ __launch_bounds__(256) void k_scan_c(int* __restrict__ off, const int* __restrict__ bsum, int n){
  int i = blockIdx.x*256+threadIdx.x;
  if (i<n) off[i] += bsum[blockIdx.x];
}

__global__ __launch_bounds__(256) void k_scatter(const int* __restrict__ d, const int* __restrict__ off,
                                                 int* __restrict__ cnt, int* __restrict__ eid, int E){
  int i = blockIdx.x*256+threadIdx.x;
  if (i<E){ int dd = d[i]; int p = off[dd] + atomicAdd(&cnt[dd],1); eid[p]=i; }
}

// One wave per destination node: edge softmax (2 passes) + weighted aggregation + residual + bias + head-max.
// el/er have row stride 32 (slices of the ecat [N,32] matrix).
__global__ __launch_bounds__(256) void k_gat_agg(const int* __restrict__ off, const int* __restrict__ eid,
    const int* __restrict__ srcArr, const float* __restrict__ el, const float* __restrict__ er,
    const u16* __restrict__ fs, const float* __restrict__ hv, const float* __restrict__ bias,
    float* __restrict__ hout, int addFlag, int n){
  int w = (blockIdx.x*256 + threadIdx.x) >> 6;
  int lane = threadIdx.x & 63;
  if (w >= n) return;
  int h = lane >> 3;                  // lane covers elements [16*lane, 16*lane+16) of the 1024-vec
  float ern = er[(size_t)w*32 + h];
  int lo = off[w], hi = off[w+1];
  float mh = -1e30f;
  for (int idx=lo; idx<hi; ++idx){
    int s = srcArr[eid[idx]];
    float lv = el[(size_t)s*32 + h] + ern;
    lv = (lv >= 0.f) ? lv : NEG_SLOPE*lv;
    mh = fmaxf(mh, lv);
  }
  float denom = 0.f;
  float acc[16];
  #pragma unroll
  for (int j=0;j<16;j++) acc[j]=0.f;
  for (int idx=lo; idx<hi; ++idx){
    int s = srcArr[eid[idx]];
    float lv = el[(size_t)s*32 + h] + ern;
    lv = (lv >= 0.f) ? lv : NEG_SLOPE*lv;
    float wt = expf(lv - mh);
    denom += wt;
    const bf16x8* fr = (const bf16x8*)(const void*)(fs + (size_t)s*HDIM + lane*16);
    bf16x8 v0 = fr[0], v1 = fr[1];
    #pragma unroll
    for (int j=0;j<8;j++){
      acc[j]   += wt * bf2f((unsigned short)v0[j]);
      acc[8+j] += wt * bf2f((unsigned short)v1[j]);
    }
  }
  float inv = (denom > 0.f) ? 1.f/denom : 0.f;
  int dbase = (lane & 7) * 16;
  #pragma unroll
  for (int j=0;j<16;j++)
    acc[j] = acc[j]*inv + hv[(size_t)w*DD + dbase + j] + bias[lane*16 + j];
  // max over heads: lanes differing in bits 3..5 share (d), vary h
  #pragma unroll
  for (int m=8; m<64; m<<=1){
    #pragma unroll
    for (int j=0;j<16;j++){
      float o = __shfl_xor(acc[j], m);
      acc[j] = fmaxf(acc[j], o);
    }
  }
  if (lane < 8){
    if (addFlag){
      #pragma unroll
      for (int j=0;j<16;j++) hout[(size_t)w*DD + lane*16 + j] += acc[j];
    } else {
      #pragma unroll
      for (int j=0;j<16;j++) hout[(size_t)w*DD + lane*16 + j] = acc[j];
    }
  }
}

// hout = normalize(hin) rowwise
__global__ __launch_bounds__(256) void k_h(const float* __restrict__ hin, float* __restrict__ hout, int n){
  int w = (blockIdx.x*256 + threadIdx.x) >> 6;
  int lane = threadIdx.x & 63;
  if (w>=n) return;
  float2 v = *(const float2*)(hin + (size_t)w*DD + lane*2);
  float ss = v.x*v.x + v.y*v.y;
  #pragma unroll
  for (int m=1;m<64;m<<=1) ss += __shfl_xor(ss,m);
  float inv = 1.f/fmaxf(sqrtf(ss),1e-12f);
  float2 o; o.x=v.x*inv; o.y=v.y*inv;
  *(float2*)(hout + (size_t)w*DD + lane*2) = o;
}

// cat[i] = [ h[agg_src[i]] | pos_emb[pid[i]] ]  (bf16, [EAGG,256]); 4 elems/thread
__global__ __launch_bounds__(256) void k_cat(const float* __restrict__ h, const float* __restrict__ pemb,
    const int* __restrict__ pid, const int* __restrict__ asrc, u16* __restrict__ cat){
  int idx = blockIdx.x*256 + threadIdx.x;
  if (idx >= EAGG*DD/4) return;
  int i = idx >> 5;           // row  (DD/4 = 32 chunks per row)
  int c = (idx & 31) * 4;     // col
  int s = asrc[i], p = pid[i];
  float4 a = *(const float4*)(h + (size_t)s*DD + c);
  float4 b = *(const float4*)(pemb + (size_t)p*DD + c);
  u16x4 oa = {f2bf(a.x),f2bf(a.y),f2bf(a.z),f2bf(a.w)};
  u16x4 ob = {f2bf(b.x),f2bf(b.y),f2bf(b.z),f2bf(b.w)};
  *(u16x4*)(void*)(cat + (size_t)i*256 + c)      = oa;
  *(u16x4*)(void*)(cat + (size_t)i*256 + DD + c) = ob;
}

// w[i] = sum_j tanh(ep[i,j]) * target_emb[tid[agg_dst[i]], j]
__global__ __launch_bounds__(256) void k_w(const float* __restrict__ ep, const int* __restrict__ adst,
    const int* __restrict__ tid_, const float* __restrict__ temb, float* __restrict__ w){
  int i = (blockIdx.x*256 + threadIdx.x) >> 6;
  int lane = threadIdx.x & 63;
  if (i >= EAGG) return;
  int t = adst[i];
  int tt = tid_[t];
  float e0 = tanhf(ep[(size_t)i*DD + lane*2]);
  float e1 = tanhf(ep[(size_t)i*DD + lane*2 + 1]);
  float2 te = *(const float2*)(temb + (size_t)tt*DD + lane*2);
  float s = e0*te.x + e1*te.y;
  #pragma unroll
  for (int m=1;m<64;m<<=1) s += __shfl_xor(s,m);
  if (lane==0) w[i] = s;
}

__device__ __forceinline__ int lbound(const int* a, int n, int key){
  int lo=0, hi=n;
  while (lo<hi){ int mid=(lo+hi)>>1; if (a[mid]<key) lo=mid+1; else hi=mid; }
  return lo;
}

// per-target: sr_g (segment sum over sorted agg_dst), concat with h[last], matmul fc_sr, normalize -> nsr bf16
__global__ __launch_bounds__(256) void k_sr(const float* __restrict__ h, const float* __restrict__ w,
    const int* __restrict__ asrc, const int* __restrict__ adst, const int* __restrict__ lastn,
    const float* __restrict__ fcsr, u16* __restrict__ nsr){
  __shared__ float cat[256];
  __shared__ float red[128];
  __shared__ int lohi[2];
  int t = blockIdx.x, tid = threadIdx.x;
  if (tid == 0){ lohi[0] = lbound(adst, EAGG, t); lohi[1] = lbound(adst, EAGG, t+1); }
  __syncthreads();
  int lo = lohi[0], hi = lohi[1];
  if (tid < DD){
    float a = 0.f;
    for (int i=lo;i<hi;++i) a += h[(size_t)asrc[i]*DD + tid] * w[i];
    cat[tid] = a;
  } else {
    int d = tid - DD;
    cat[DD + d] = h[(size_t)lastn[t]*DD + d];
  }
  __syncthreads();
  float s = 0.f;
  if (tid < DD){
    const float* row = fcsr + (size_t)tid*256;
    #pragma unroll 8
    for (int k=0;k<256;++k) s += cat[k]*row[k];
    red[tid] = s*s;
  }
  __syncthreads();
  for (int st=64; st>0; st>>=1){
    if (tid < st) red[tid] += red[tid+st];
    __syncthreads();
  }
  if (tid < DD){
    float inv = 1.f/fmaxf(sqrtf(red[0]),1e-12f);
    nsr[(size_t)t*DD + tid] = f2bf(s*inv);
  }
}

extern "C" void kernel_launch(void* const* d_in, const int* in_sizes, int n_in,
                              void* d_out, int out_size, void* d_ws, size_t ws_size,
                              hipStream_t stream){
  (void)in_sizes; (void)n_in; (void)out_size; (void)ws_size;
  const int*   iid   = (const int*)d_in[0];
  const int*   tid_  = (const int*)d_in[1];
  const int*   pid   = (const int*)d_in[2];
  const int*   src_i = (const int*)d_in[3];
  const int*   dst_i = (const int*)d_in[4];
  const int*   asrc  = (const int*)d_in[5];
  const int*   adst  = (const int*)d_in[6];
  const int*   lastn = (const int*)d_in[7];
  const float* emb   = (const float*)d_in[8];
  const float* pemb  = (const float*)d_in[9];
  const float* temb  = (const float*)d_in[10];
  const float* fc1   = (const float*)d_in[11];
  const float* al1   = (const float*)d_in[12];
  const float* ar1   = (const float*)d_in[13];
  const float* b1    = (const float*)d_in[14];
  const float* fc2   = (const float*)d_in[15];
  const float* al2   = (const float*)d_in[16];
  const float* ar2   = (const float*)d_in[17];
  const float* b2    = (const float*)d_in[18];
  const float* qw    = (const float*)d_in[19];
  const float* fcsr  = (const float*)d_in[20];

  char* ws = (char*)d_ws;
  size_t o = 0;
  auto alc = [&](size_t b)->char*{ char* r = ws + o; o += (b + 511) & ~(size_t)511; return r; };
  float* hv   = (float*)alc((size_t)NITEMS*DD*4);      // 42 MB  (later reused to hold h)
  u16*   hvb  = (u16*)  alc((size_t)NITEMS*DD*2);      // 21 MB
  float* h1   = (float*)alc((size_t)NITEMS*DD*4);      // 42 MB  (h1, then h1+h2)
  float* ecat = (float*)alc((size_t)NITEMS*32*4);      // 10.5 MB (el1|er1|el2|er2)
  int*   off  = (int*)  alc((size_t)(NITEMS+1)*4);
  int*   cnt  = (int*)  alc((size_t)NITEMS*4);
  int*   bsum = (int*)  alc((size_t)512*4);
  int*   eid  = (int*)  alc((size_t)EINT*4);
  u16*   wfc  = (u16*)  alc((size_t)HDIM*DD*2);
  u16*   qwb  = (u16*)  alc((size_t)DD*256*2);
  u16*   Umat = (u16*)  alc((size_t)128*DD*2);
  float* wv   = (float*)alc((size_t)EAGG*4);
  u16*   nsr  = (u16*)  alc((size_t)NT*DD*2);
  u16*   nemb = (u16*)  alc((size_t)NVPAD*DD*2);       // 10 MB
  u16*   fsb  = (u16*)  alc((size_t)NITEMS*HDIM*2);    // 168 MB (fs; later aliased by cat + e_pre)
  u16*   catb = fsb;
  float* ep   = (float*)((char*)fsb + (size_t)EAGG*256*2);

  const int NB = NITEMS/256;   // 320 scan blocks

  // common precompute
  hipMemsetAsync(Umat, 0, (size_t)128*DD*2, stream);
  k_prep_u<<<8, 128, 0, stream>>>(fc1, al1, ar1, fc2, al2, ar2, Umat);
  k_hv  <<<NITEMS/4, 256, 0, stream>>>(emb, iid, hv, hvb, NITEMS);
  k_nemb<<<NVPAD/4,  256, 0, stream>>>(emb, nemb);
  // ecat[n, 0:32] = hv[n] @ U^T   (el1|er1|el2|er2)
  gemm_nt<0><<<dim3(NITEMS/128, 1), 256, 0, stream>>>(hvb, Umat, ecat, NITEMS, 128, DD, 1.f, 32, 32);

  // ---- GAT1 (graph: src_i -> dst_i) ----
  k_cast<<<(HDIM*DD+255)/256, 256, 0, stream>>>(fc1, wfc, HDIM*DD);
  gemm_nt<1><<<dim3(NITEMS/128, HDIM/128), 256, 0, stream>>>(hvb, wfc, fsb, NITEMS, HDIM, DD, 1.f, HDIM, HDIM);
  hipMemsetAsync(cnt, 0, (size_t)NITEMS*4, stream);
  k_deg<<<(EINT+255)/256, 256, 0, stream>>>(dst_i, cnt, EINT);
  k_scan_a<<<NB, 256, 0, stream>>>(cnt, off, bsum, cnt, NITEMS);
  k_scan_b<<<1, 512, 0, stream>>>(bsum, off, NB, NITEMS);
  k_scan_c<<<NB, 256, 0, stream>>>(off, bsum, NITEMS);
  k_scatter<<<(EINT+255)/256, 256, 0, stream>>>(dst_i, off, cnt, eid, EINT);
  k_gat_agg<<<NITEMS/4, 256, 0, stream>>>(off, eid, src_i, ecat+0, ecat+8, fsb, hv, b1, h1, 0, NITEMS);

  // ---- GAT2 (reversed graph: dst_i -> src_i), accumulate into h1 ----
  k_cast<<<(HDIM*DD+255)/256, 256, 0, stream>>>(fc2, wfc, HDIM*DD);
  gemm_nt<1><<<dim3(NITEMS/128, HDIM/128), 256, 0, stream>>>(hvb, wfc, fsb, NITEMS, HDIM, DD, 1.f, HDIM, HDIM);
  hipMemsetAsync(cnt, 0, (size_t)NITEMS*4, stream);
  k_deg<<<(EINT+255)/256, 256, 0, stream>>>(src_i, cnt, EINT);
  k_scan_a<<<NB, 256, 0, stream>>>(cnt, off, bsum, cnt, NITEMS);
  k_scan_b<<<1, 512, 0, stream>>>(bsum, off, NB, NITEMS);
  k_scan_c<<<NB, 256, 0, stream>>>(off, bsum, NITEMS);
  k_scatter<<<(EINT+255)/256, 256, 0, stream>>>(src_i, off, cnt, eid, EINT);
  k_gat_agg<<<NITEMS/4, 256, 0, stream>>>(off, eid, dst_i, ecat+16, ecat+24, fsb, hv, b2, h1, 1, NITEMS);

  // h = normalize(h1+h2)  (stored into hv buffer, fs region now free)
  k_h<<<NITEMS/4, 256, 0, stream>>>(h1, hv, NITEMS);

  // ---- PosAggregator ----
  k_cast<<<(DD*256+255)/256, 256, 0, stream>>>(qw, qwb, DD*256);
  k_cat<<<(EAGG*DD/4)/256, 256, 0, stream>>>(hv, pemb, pid, asrc, catb);
  gemm_nt<0><<<dim3(EAGG/128, 1), 256, 0, stream>>>(catb, qwb, ep, EAGG, DD, 256, 1.f, DD, DD);
  k_w<<<EAGG/4, 256, 0, stream>>>(ep, adst, tid_, temb, wv);
  k_sr<<<NT, 256, 0, stream>>>(hv, wv, asrc, adst, lastn, fcsr, nsr);

  // ---- scores = SCALE * nsr @ nemb^T ----
  gemm_nt<0><<<dim3(NT/128, NVPAD/128), 256, 0, stream>>>(nsr, nemb, (float*)d_out, NT, NVPAD, DD, SCALE, NV, NV);
}